// Round 9
// baseline (288.502 us; speedup 1.0000x reference)
//
#include <hip/hip_runtime.h>
#include <cstdint>

#define B_ 16
#define C_ 1024
#define Q_ 128
#define H_ 768
#define OSTR (4 * H_)  // 3072

typedef __attribute__((ext_vector_type(8))) short bf16x8;
typedef __attribute__((ext_vector_type(4))) float f32x4;
typedef __attribute__((ext_vector_type(4))) int int4v;

__device__ __forceinline__ unsigned short f2bf(float x) {
  union { float f; unsigned u; } v; v.f = x;
  unsigned r = v.u + 0x7FFFu + ((v.u >> 16) & 1u);
  return (unsigned short)(r >> 16);
}
__device__ __forceinline__ unsigned pk2(float a, float b) {
  return (unsigned)f2bf(a) | ((unsigned)f2bf(b) << 16);
}
__device__ __forceinline__ float bf2f(unsigned short u) {
  union { unsigned u; float f; } t; t.u = ((unsigned)u) << 16; return t.f;
}

// four-segment fp32 -> bf16 (context, query, Wc, Wq) in one launch
__global__ __launch_bounds__(256) void f2bf4_kernel(
    const float* __restrict__ s0, unsigned short* __restrict__ d0, int n0,
    const float* __restrict__ s1, unsigned short* __restrict__ d1, int n1,
    const float* __restrict__ s2, unsigned short* __restrict__ d2, int n2,
    const float* __restrict__ s3, unsigned short* __restrict__ d3, int n3) {
  int i = blockIdx.x * 256 + threadIdx.x;
  const float* s;
  unsigned short* d;
  if (i < n0) { s = s0; d = d0; }
  else if ((i -= n0) < n1) { s = s1; d = d1; }
  else if ((i -= n1) < n2) { s = s2; d = d2; }
  else if ((i -= n2) < n3) { s = s3; d = d3; }
  else return;
  float4 a = ((const float4*)s)[2 * i];
  float4 b = ((const float4*)s)[2 * i + 1];
  int4v o;
  o[0] = (int)pk2(a.x, a.y); o[1] = (int)pk2(a.z, a.w);
  o[2] = (int)pk2(b.x, b.y); o[3] = (int)pk2(b.z, b.w);
  ((int4v*)d)[i] = o;
}

// Unified NT GEMM. DIAGNOSTIC: grid may be replicated x(grid/nreal); block-copies
// with copy>0 do full loads+MFMA but skip all global stores (runtime-uniform
// guard -> no DCE of compute). Real work identical to R8.
// MODE 0: ctx proj  -> fp32 out (stride OSTR) + bf16 ctxp (ob1)
// MODE 1: qry proj  -> bf16 qryW=v*watt (ob1) + bf16 qryT transposed (ob2)
// MODE 2: sim       -> fused row-softmax -> bf16 alpha (ob1) + q2c
// MODE 3: PV        -> epilogue writes a, c=ctx*a, d=ctx*bvec to out
template <int MODE>
__global__ __launch_bounds__(256) void gemm_uni(
    const unsigned short* __restrict__ A, const unsigned short* __restrict__ Bm,
    const float* __restrict__ bias, float* __restrict__ out32,
    unsigned short* __restrict__ ob1, unsigned short* __restrict__ ob2,
    const float* __restrict__ watt, const float* __restrict__ cmask,
    const float* __restrict__ qmask, float* __restrict__ q2c,
    const float* __restrict__ bvec, int K, int qchunk, int nreal) {
  __shared__ __align__(16) unsigned short As[128 * 32];
  __shared__ __align__(16) unsigned short Ws[128 * 32];
  __shared__ float pmS[2][128];
  __shared__ float psS[2][128];
  const int tid = threadIdx.x;
  const int lane = tid & 63;
  const int w = tid >> 6;
  int bid = (int)blockIdx.x;
  const int copy = bid / nreal;
  bid -= copy * nreal;
  const bool st = (copy == 0);
  const int orig = (bid & 7) * qchunk + (bid >> 3);
  const int wr = (w >> 1) * 64;
  const int wc = (w & 1) * 64;
  const int fr = lane & 15;
  const int fq = lane >> 4;

  int gm, gn, bb;
  const unsigned short *Ap, *Bp;
  if constexpr (MODE == 0 || MODE == 1) {
    gm = (orig / 6) * 128; gn = (orig % 6) * 128; bb = 0;
    Ap = A + (size_t)gm * K; Bp = Bm + (size_t)gn * K;
  } else if constexpr (MODE == 2) {
    bb = orig >> 3; gm = bb * C_ + (orig & 7) * 128; gn = 0;
    Ap = A + (size_t)gm * K; Bp = Bm + (size_t)bb * Q_ * K;
  } else {
    bb = orig / 48; const int rem = orig % 48;
    gm = bb * C_ + (rem / 6) * 128; gn = (rem % 6) * 128;
    Ap = A + (size_t)gm * K; Bp = Bm + ((size_t)bb * H_ + gn) * K;
  }

  auto stage = [&](const unsigned short* __restrict__ G, unsigned short* S, int k0) {
#pragma unroll
    for (int r = 0; r < 2; ++r) {
      const int c = r * 256 + w * 64 + lane;
      const int row = c >> 2, sub = c & 3;
      const unsigned short* g = G + (size_t)row * K + k0 + sub * 8;
      unsigned short* l = S + (size_t)(r * 256 + w * 64) * 8;  // wave-uniform base
      __builtin_amdgcn_global_load_lds(
          (const __attribute__((address_space(1))) void*)g,
          (__attribute__((address_space(3))) void*)l, 16, 0, 0);
    }
  };

  f32x4 acc[4][4];
#pragma unroll
  for (int i = 0; i < 4; ++i)
#pragma unroll
    for (int j = 0; j < 4; ++j)
#pragma unroll
      for (int e = 0; e < 4; ++e) acc[i][j][e] = 0.f;

  for (int k0 = 0; k0 < K; k0 += 32) {
    stage(Ap, As, k0);
    stage(Bp, Ws, k0);
    __syncthreads();
    bf16x8 af[4], wf[4];
#pragma unroll
    for (int i = 0; i < 4; ++i)
      af[i] = *(const bf16x8*)(As + (wr + i * 16 + fr) * 32 + fq * 8);
#pragma unroll
    for (int j = 0; j < 4; ++j)
      wf[j] = *(const bf16x8*)(Ws + (wc + j * 16 + fr) * 32 + fq * 8);
#pragma unroll
    for (int i = 0; i < 4; ++i)
#pragma unroll
      for (int j = 0; j < 4; ++j)
        acc[i][j] = __builtin_amdgcn_mfma_f32_16x16x32_bf16(af[i], wf[j], acc[i][j], 0, 0, 0);
    __syncthreads();
  }

  if constexpr (MODE == 0) {
    if (st) {
#pragma unroll
      for (int j = 0; j < 4; ++j) {
        const int n = gn + wc + j * 16 + fr;
        const float bias_n = bias[n];
#pragma unroll
        for (int i = 0; i < 4; ++i) {
#pragma unroll
          for (int r = 0; r < 4; ++r) {
            const size_t m = (size_t)gm + wr + i * 16 + fq * 4 + r;
            float v = acc[i][j][r] + bias_n;
            out32[m * OSTR + n] = v;
            ob1[m * H_ + n] = f2bf(v);
          }
        }
      }
    }
  } else if constexpr (MODE == 1) {
    if (st) {
#pragma unroll
      for (int i = 0; i < 4; ++i) {
#pragma unroll
        for (int j = 0; j < 4; ++j) {
          const int n = gn + wc + j * 16 + fr;
          const float bias_n = bias[n];
          const float wv = watt[n];
          ushort4 t4;
#pragma unroll
          for (int r = 0; r < 4; ++r) {
            const size_t m = (size_t)gm + wr + i * 16 + fq * 4 + r;
            float v = acc[i][j][r] + bias_n;
            ob1[m * H_ + n] = f2bf(v * wv);
            (&t4.x)[r] = f2bf(v);
          }
          const int bidx = gm >> 7;
          const int q0 = wr + i * 16 + fq * 4;
          *(ushort4*)(ob2 + ((size_t)bidx * H_ + n) * Q_ + q0) = t4;
        }
      }
    }
  } else if constexpr (MODE == 2) {
    // fused row-softmax over the 128-wide q dimension (one tile = full row)
    float red[4][4];
#pragma unroll
    for (int i = 0; i < 4; ++i)
#pragma unroll
      for (int r = 0; r < 4; ++r) {
        float mx = acc[i][0][r];
#pragma unroll
        for (int j = 1; j < 4; ++j) mx = fmaxf(mx, acc[i][j][r]);
        mx = fmaxf(mx, __shfl_xor(mx, 1));
        mx = fmaxf(mx, __shfl_xor(mx, 2));
        mx = fmaxf(mx, __shfl_xor(mx, 4));
        mx = fmaxf(mx, __shfl_xor(mx, 8));
        red[i][r] = mx;
      }
    if (fr == 0) {
#pragma unroll
      for (int i = 0; i < 4; ++i)
#pragma unroll
        for (int r = 0; r < 4; ++r)
          pmS[w & 1][wr + i * 16 + fq * 4 + r] = red[i][r];
    }
    __syncthreads();
    float qm[4];
#pragma unroll
    for (int j = 0; j < 4; ++j) qm[j] = qmask[bb * Q_ + wc + j * 16 + fr];
#pragma unroll
    for (int i = 0; i < 4; ++i)
#pragma unroll
      for (int r = 0; r < 4; ++r) {
        const int lr = wr + i * 16 + fq * 4 + r;
        const float M = fmaxf(pmS[0][lr], pmS[1][lr]);
        if ((w & 1) == 0 && fr == 0 && st) q2c[gm + lr] = M;
        float s = 0.f;
#pragma unroll
        for (int j = 0; j < 4; ++j) {
          acc[i][j][r] = __expf(acc[i][j][r] - M);
          s += acc[i][j][r];
        }
        s += __shfl_xor(s, 1); s += __shfl_xor(s, 2);
        s += __shfl_xor(s, 4); s += __shfl_xor(s, 8);
        red[i][r] = s;
      }
    if (fr == 0) {
#pragma unroll
      for (int i = 0; i < 4; ++i)
#pragma unroll
        for (int r = 0; r < 4; ++r)
          psS[w & 1][wr + i * 16 + fq * 4 + r] = red[i][r];
    }
    __syncthreads();
    if (st) {
#pragma unroll
      for (int i = 0; i < 4; ++i)
#pragma unroll
        for (int r = 0; r < 4; ++r) {
          const int lr = wr + i * 16 + fq * 4 + r;
          const float S = psS[0][lr] + psS[1][lr];
          const float inv = cmask[gm + lr] / S;
#pragma unroll
          for (int j = 0; j < 4; ++j) {
            const int lc = wc + j * 16 + fr;
            ob1[(size_t)(gm + lr) * Q_ + lc] = f2bf(acc[i][j][r] * inv * qm[j]);
          }
        }
    }
  } else {  // MODE 3: PV epilogue; ob1 = ctxp (bf16, read)
    if (st) {
#pragma unroll
      for (int j = 0; j < 4; ++j) {
        const int n = gn + wc + j * 16 + fr;
        const float bv = bvec[bb * H_ + n];
#pragma unroll
        for (int i = 0; i < 4; ++i) {
#pragma unroll
          for (int r = 0; r < 4; ++r) {
            const size_t m = (size_t)gm + wr + i * 16 + fq * 4 + r;
            const float av = acc[i][j][r];
            const float cx = bf2f(ob1[m * H_ + n]);
            float* row = out32 + m * OSTR;
            row[H_ + n] = av;
            row[2 * H_ + n] = cx * av;
            row[3 * H_ + n] = cx * bv;
          }
        }
      }
    }
  }
}

// beta softmax over c (per batch) + bvec[b,p] = sum_c beta[c]*ctx_bf16[b,c,p]
__global__ __launch_bounds__(256) void beta_bvec_kernel(
    const unsigned short* __restrict__ ctxp, const float* __restrict__ q2c,
    const float* __restrict__ cmask, float* __restrict__ bvec, int nreal) {
  __shared__ float sh[C_];
  __shared__ float red[256];
  const int tid = threadIdx.x;
  int bid = (int)blockIdx.x;
  const int copy = bid / nreal;
  bid -= copy * nreal;
  const int b = bid / 12;
  const int p0 = (bid % 12) * 64;
  float v[4];
  float lm = -1e30f;
#pragma unroll
  for (int i = 0; i < 4; ++i) {
    v[i] = q2c[b * C_ + i * 256 + tid];
    lm = fmaxf(lm, v[i]);
  }
  red[tid] = lm;
  __syncthreads();
  for (int off = 128; off > 0; off >>= 1) {
    if (tid < off) red[tid] = fmaxf(red[tid], red[tid + off]);
    __syncthreads();
  }
  const float m = red[0];
  __syncthreads();
  float ls = 0.f;
#pragma unroll
  for (int i = 0; i < 4; ++i) {
    float e = __expf(v[i] - m);
    sh[i * 256 + tid] = e * cmask[b * C_ + i * 256 + tid];
    ls += e;
  }
  red[tid] = ls;
  __syncthreads();
  for (int off = 128; off > 0; off >>= 1) {
    if (tid < off) red[tid] += red[tid + off];
    __syncthreads();
  }
  const float denom = red[0];
  const int pp = tid & 63;
  const int cg = tid >> 6;
  const unsigned short* base = ctxp + ((size_t)(b * C_ + cg)) * H_ + p0 + pp;
  float acc = 0.f;
#pragma unroll 4
  for (int c = cg; c < C_; c += 4) {
    acc += sh[c] * bf2f(*base);
    base += (size_t)4 * H_;
  }
  __syncthreads();
  red[tid] = acc;
  __syncthreads();
  if (tid < 64 && copy == 0)
    bvec[b * H_ + p0 + tid] =
        (red[tid] + red[tid + 64] + red[tid + 128] + red[tid + 192]) / denom;
}

extern "C" void kernel_launch(void* const* d_in, const int* in_sizes, int n_in,
                              void* d_out, int out_size, void* d_ws, size_t ws_size,
                              hipStream_t stream) {
  const float* context = (const float*)d_in[0];
  const float* cmask   = (const float*)d_in[1];
  const float* query   = (const float*)d_in[2];
  const float* qmask   = (const float*)d_in[3];
  const float* Wc      = (const float*)d_in[4];
  const float* bc      = (const float*)d_in[5];
  const float* Wq      = (const float*)d_in[6];
  const float* bq      = (const float*)d_in[7];
  const float* w_att   = (const float*)d_in[8];
  float* out = (float*)d_out;

  unsigned short* ws_ctxb = (unsigned short*)d_ws;
  unsigned short* ws_qinb = ws_ctxb + (size_t)B_ * C_ * H_;
  unsigned short* ws_Wcb  = ws_qinb + (size_t)B_ * Q_ * H_;
  unsigned short* ws_Wqb  = ws_Wcb + (size_t)H_ * H_;
  unsigned short* ws_qryW = ws_Wqb + (size_t)H_ * H_;
  unsigned short* ws_qryT = ws_qryW + (size_t)B_ * Q_ * H_;
  unsigned short* ws_ctxp = ws_qryT + (size_t)B_ * H_ * Q_;
  float* ws_q2c  = (float*)(ws_ctxp + (size_t)B_ * C_ * H_);
  float* ws_bvec = ws_q2c + (size_t)B_ * C_;
  unsigned short* ws_alpha = ws_qinb;  // overlays dead qinb+Wcb

  {
    const int n0 = B_ * C_ * H_ / 8;
    const int n1 = B_ * Q_ * H_ / 8;
    const int n2 = H_ * H_ / 8;
    const int n3 = n2;
    const int tot = n0 + n1 + n2 + n3;
    f2bf4_kernel<<<(tot + 255) / 256, 256, 0, stream>>>(
        context, ws_ctxb, n0, query, ws_qinb, n1, Wc, ws_Wcb, n2, Wq, ws_Wqb, n3);
  }
  // qry projection (not replicated)
  gemm_uni<1><<<96, 256, 0, stream>>>(
      ws_qinb, ws_Wqb, bq, nullptr, ws_qryW, ws_qryT, w_att,
      nullptr, nullptr, nullptr, nullptr, H_, 12, 96);
  // ctx projection — DIAGNOSTIC x4 (768 real)
  gemm_uni<0><<<768 * 4, 256, 0, stream>>>(
      ws_ctxb, ws_Wcb, bc, out, ws_ctxp, nullptr, nullptr,
      nullptr, nullptr, nullptr, nullptr, H_, 96, 768);
  // sim GEMM + fused softmax — DIAGNOSTIC x8 (128 real)
  gemm_uni<2><<<128 * 8, 256, 0, stream>>>(
      ws_ctxp, ws_qryW, nullptr, nullptr, ws_alpha, nullptr, nullptr,
      cmask, qmask, ws_q2c, nullptr, H_, 16, 128);
  // beta softmax + bvec — DIAGNOSTIC x4 (192 real)
  beta_bvec_kernel<<<192 * 4, 256, 0, stream>>>(ws_ctxp, ws_q2c, cmask, ws_bvec, 192);
  // PV GEMM — DIAGNOSTIC x4 (768 real)
  gemm_uni<3><<<768 * 4, 256, 0, stream>>>(
      ws_alpha, ws_qryT, nullptr, out, ws_ctxp, nullptr, nullptr,
      nullptr, nullptr, nullptr, ws_bvec, Q_, 96, 768);
}

// Round 10
// 178.910 us; speedup vs baseline: 1.6126x; 1.6126x over previous
//
#include <hip/hip_runtime.h>
#include <cstdint>

#define B_ 16
#define C_ 1024
#define Q_ 128
#define H_ 768
#define OSTR (4 * H_)  // 3072

typedef __attribute__((ext_vector_type(8))) short bf16x8;
typedef __attribute__((ext_vector_type(4))) float f32x4;
typedef __attribute__((ext_vector_type(4))) int int4v;

__device__ __forceinline__ unsigned short f2bf(float x) {
  union { float f; unsigned u; } v; v.f = x;
  unsigned r = v.u + 0x7FFFu + ((v.u >> 16) & 1u);
  return (unsigned short)(r >> 16);
}
__device__ __forceinline__ unsigned pk2(float a, float b) {
  return (unsigned)f2bf(a) | ((unsigned)f2bf(b) << 16);
}
__device__ __forceinline__ float bf2f(unsigned short u) {
  union { unsigned u; float f; } t; t.u = ((unsigned)u) << 16; return t.f;
}

// four-segment fp32 -> bf16 (context, query, Wc, Wq) in one launch
__global__ __launch_bounds__(256) void f2bf4_kernel(
    const float* __restrict__ s0, unsigned short* __restrict__ d0, int n0,
    const float* __restrict__ s1, unsigned short* __restrict__ d1, int n1,
    const float* __restrict__ s2, unsigned short* __restrict__ d2, int n2,
    const float* __restrict__ s3, unsigned short* __restrict__ d3, int n3) {
  int i = blockIdx.x * 256 + threadIdx.x;
  const float* s;
  unsigned short* d;
  if (i < n0) { s = s0; d = d0; }
  else if ((i -= n0) < n1) { s = s1; d = d1; }
  else if ((i -= n1) < n2) { s = s2; d = d2; }
  else if ((i -= n2) < n3) { s = s3; d = d3; }
  else return;
  float4 a = ((const float4*)s)[2 * i];
  float4 b = ((const float4*)s)[2 * i + 1];
  int4v o;
  o[0] = (int)pk2(a.x, a.y); o[1] = (int)pk2(a.z, a.w);
  o[2] = (int)pk2(b.x, b.y); o[3] = (int)pk2(b.z, b.w);
  ((int4v*)d)[i] = o;
}

// Unified NT GEMM (128x128 tile, BK=32, 4 waves, global_load_lds staging,
// bijective XCD-chunked swizzle).
// MODE 0: ctx proj -> fp32 out (stride OSTR) + bf16 ctxp (ob1)   [LDS-coalesced epi]
// MODE 1: qry proj -> bf16 qryW=v*watt (ob1) + bf16 qryT (ob2)
// MODE 2: sim      -> fused row-softmax -> bf16 alpha (ob1) + q2c
// MODE 3: PV       -> a, c=ctx*a, d=ctx*bvec to out              [LDS-coalesced epi]
template <int MODE>
__global__ __launch_bounds__(256) void gemm_uni(
    const unsigned short* __restrict__ A, const unsigned short* __restrict__ Bm,
    const float* __restrict__ bias, float* __restrict__ out32,
    unsigned short* __restrict__ ob1, unsigned short* __restrict__ ob2,
    const float* __restrict__ watt, const float* __restrict__ cmask,
    const float* __restrict__ qmask, float* __restrict__ q2c,
    const float* __restrict__ bvec, int K, int qchunk) {
  // modes 0/3 reuse the staging LDS as a 128x132 fp32 transpose buffer
  __shared__ __align__(16) unsigned char smem[(MODE == 0 || MODE == 3) ? 128 * 132 * 4 : 16384];
  __shared__ float pmS[2][128];
  __shared__ float psS[2][128];
  unsigned short* As = (unsigned short*)smem;
  unsigned short* Ws = (unsigned short*)(smem + 8192);
  const int tid = threadIdx.x;
  const int lane = tid & 63;
  const int w = tid >> 6;
  const int orig = ((int)blockIdx.x & 7) * qchunk + ((int)blockIdx.x >> 3);
  const int wr = (w >> 1) * 64;
  const int wc = (w & 1) * 64;
  const int fr = lane & 15;
  const int fq = lane >> 4;

  int gm, gn, bb;
  const unsigned short *Ap, *Bp;
  if constexpr (MODE == 0 || MODE == 1) {
    gm = (orig / 6) * 128; gn = (orig % 6) * 128; bb = 0;
    Ap = A + (size_t)gm * K; Bp = Bm + (size_t)gn * K;
  } else if constexpr (MODE == 2) {
    bb = orig >> 3; gm = bb * C_ + (orig & 7) * 128; gn = 0;
    Ap = A + (size_t)gm * K; Bp = Bm + (size_t)bb * Q_ * K;
  } else {
    bb = orig / 48; const int rem = orig % 48;
    gm = bb * C_ + (rem / 6) * 128; gn = (rem % 6) * 128;
    Ap = A + (size_t)gm * K; Bp = Bm + ((size_t)bb * H_ + gn) * K;
  }

  auto stage = [&](const unsigned short* __restrict__ G, unsigned short* S, int k0) {
#pragma unroll
    for (int r = 0; r < 2; ++r) {
      const int c = r * 256 + w * 64 + lane;
      const int row = c >> 2, sub = c & 3;
      const unsigned short* g = G + (size_t)row * K + k0 + sub * 8;
      unsigned short* l = S + (size_t)(r * 256 + w * 64) * 8;  // wave-uniform base
      __builtin_amdgcn_global_load_lds(
          (const __attribute__((address_space(1))) void*)g,
          (__attribute__((address_space(3))) void*)l, 16, 0, 0);
    }
  };

  f32x4 acc[4][4];
#pragma unroll
  for (int i = 0; i < 4; ++i)
#pragma unroll
    for (int j = 0; j < 4; ++j)
#pragma unroll
      for (int e = 0; e < 4; ++e) acc[i][j][e] = 0.f;

  for (int k0 = 0; k0 < K; k0 += 32) {
    stage(Ap, As, k0);
    stage(Bp, Ws, k0);
    __syncthreads();
    bf16x8 af[4], wf[4];
#pragma unroll
    for (int i = 0; i < 4; ++i)
      af[i] = *(const bf16x8*)(As + (wr + i * 16 + fr) * 32 + fq * 8);
#pragma unroll
    for (int j = 0; j < 4; ++j)
      wf[j] = *(const bf16x8*)(Ws + (wc + j * 16 + fr) * 32 + fq * 8);
#pragma unroll
    for (int i = 0; i < 4; ++i)
#pragma unroll
      for (int j = 0; j < 4; ++j)
        acc[i][j] = __builtin_amdgcn_mfma_f32_16x16x32_bf16(af[i], wf[j], acc[i][j], 0, 0, 0);
    __syncthreads();
  }

  if constexpr (MODE == 0 || MODE == 3) {
    // ---- LDS transpose epilogue: frags -> [128][132] fp32 -> coalesced stores
    float* tr = (float*)smem;
    float bj[4];
    if constexpr (MODE == 0) {
#pragma unroll
      for (int j = 0; j < 4; ++j) bj[j] = bias[gn + wc + j * 16 + fr];
    }
#pragma unroll
    for (int i = 0; i < 4; ++i)
#pragma unroll
      for (int j = 0; j < 4; ++j)
#pragma unroll
        for (int r = 0; r < 4; ++r) {
          float v = acc[i][j][r];
          if constexpr (MODE == 0) v += bj[j];
          tr[(wr + i * 16 + fq * 4 + r) * 132 + wc + j * 16 + fr] = v;
        }
    __syncthreads();
    if constexpr (MODE == 0) {
#pragma unroll
      for (int k = 0; k < 16; ++k) {
        const int f = k * 256 + tid;
        const int row = f >> 5, c4 = (f & 31) << 2;
        float4 v = *(const float4*)&tr[row * 132 + c4];
        *(float4*)&out32[(size_t)(gm + row) * OSTR + gn + c4] = v;
      }
#pragma unroll
      for (int k = 0; k < 8; ++k) {
        const int f = k * 256 + tid;
        const int row = f >> 4, c8 = (f & 15) << 3;
        const float* s = &tr[row * 132 + c8];
        int4v o;
        o[0] = (int)pk2(s[0], s[1]); o[1] = (int)pk2(s[2], s[3]);
        o[2] = (int)pk2(s[4], s[5]); o[3] = (int)pk2(s[6], s[7]);
        *(int4v*)&ob1[(size_t)(gm + row) * H_ + gn + c8] = o;
      }
    } else {  // MODE 3: a, c=ctx*a, d=ctx*bvec  (ob1 = ctxp bf16, read)
#pragma unroll
      for (int k = 0; k < 16; ++k) {
        const int f = k * 256 + tid;
        const int row = f >> 5, c4 = (f & 31) << 2;
        float4 av = *(const float4*)&tr[row * 132 + c4];
        ushort4 cu = *(const ushort4*)&ob1[(size_t)(gm + row) * H_ + gn + c4];
        float4 bv = *(const float4*)&bvec[bb * H_ + gn + c4];
        const float cx0 = bf2f(cu.x), cx1 = bf2f(cu.y), cx2 = bf2f(cu.z), cx3 = bf2f(cu.w);
        float* rowp = out32 + (size_t)(gm + row) * OSTR + gn;
        *(float4*)&rowp[H_ + c4] = av;
        float4 cc;
        cc.x = cx0 * av.x; cc.y = cx1 * av.y; cc.z = cx2 * av.z; cc.w = cx3 * av.w;
        *(float4*)&rowp[2 * H_ + c4] = cc;
        float4 dd;
        dd.x = cx0 * bv.x; dd.y = cx1 * bv.y; dd.z = cx2 * bv.z; dd.w = cx3 * bv.w;
        *(float4*)&rowp[3 * H_ + c4] = dd;
      }
    }
  } else if constexpr (MODE == 1) {
#pragma unroll
    for (int i = 0; i < 4; ++i) {
#pragma unroll
      for (int j = 0; j < 4; ++j) {
        const int n = gn + wc + j * 16 + fr;
        const float bias_n = bias[n];
        const float wv = watt[n];
        ushort4 t4;
#pragma unroll
        for (int r = 0; r < 4; ++r) {
          const size_t m = (size_t)gm + wr + i * 16 + fq * 4 + r;
          float v = acc[i][j][r] + bias_n;
          ob1[m * H_ + n] = f2bf(v * wv);
          (&t4.x)[r] = f2bf(v);
        }
        const int bidx = gm >> 7;
        const int q0 = wr + i * 16 + fq * 4;
        *(ushort4*)(ob2 + ((size_t)bidx * H_ + n) * Q_ + q0) = t4;
      }
    }
  } else {  // MODE 2: fused row-softmax over the 128-wide q dim
    float red[4][4];
#pragma unroll
    for (int i = 0; i < 4; ++i)
#pragma unroll
      for (int r = 0; r < 4; ++r) {
        float mx = acc[i][0][r];
#pragma unroll
        for (int j = 1; j < 4; ++j) mx = fmaxf(mx, acc[i][j][r]);
        mx = fmaxf(mx, __shfl_xor(mx, 1));
        mx = fmaxf(mx, __shfl_xor(mx, 2));
        mx = fmaxf(mx, __shfl_xor(mx, 4));
        mx = fmaxf(mx, __shfl_xor(mx, 8));
        red[i][r] = mx;
      }
    if (fr == 0) {
#pragma unroll
      for (int i = 0; i < 4; ++i)
#pragma unroll
        for (int r = 0; r < 4; ++r)
          pmS[w & 1][wr + i * 16 + fq * 4 + r] = red[i][r];
    }
    __syncthreads();
    float qm[4];
#pragma unroll
    for (int j = 0; j < 4; ++j) qm[j] = qmask[bb * Q_ + wc + j * 16 + fr];
#pragma unroll
    for (int i = 0; i < 4; ++i)
#pragma unroll
      for (int r = 0; r < 4; ++r) {
        const int lr = wr + i * 16 + fq * 4 + r;
        const float M = fmaxf(pmS[0][lr], pmS[1][lr]);
        if ((w & 1) == 0 && fr == 0) q2c[gm + lr] = M;  // b_att cancels in both softmaxes
        float s = 0.f;
#pragma unroll
        for (int j = 0; j < 4; ++j) {
          acc[i][j][r] = __expf(acc[i][j][r] - M);
          s += acc[i][j][r];
        }
        s += __shfl_xor(s, 1); s += __shfl_xor(s, 2);
        s += __shfl_xor(s, 4); s += __shfl_xor(s, 8);
        red[i][r] = s;
      }
    if (fr == 0) {
#pragma unroll
      for (int i = 0; i < 4; ++i)
#pragma unroll
        for (int r = 0; r < 4; ++r)
          psS[w & 1][wr + i * 16 + fq * 4 + r] = red[i][r];
    }
    __syncthreads();
#pragma unroll
    for (int i = 0; i < 4; ++i)
#pragma unroll
      for (int r = 0; r < 4; ++r) {
        const int lr = wr + i * 16 + fq * 4 + r;
        const float S = psS[0][lr] + psS[1][lr];
        const float inv = cmask[gm + lr] / S;
#pragma unroll
        for (int j = 0; j < 4; ++j) {
          const int lc = wc + j * 16 + fr;
          ob1[(size_t)(gm + lr) * Q_ + lc] = f2bf(acc[i][j][r] * inv * qm[j]);
        }
      }
  }
}

// beta softmax over c (per batch) + bvec[b,p] = sum_c beta[c]*ctx_bf16[b,c,p]
__global__ __launch_bounds__(256) void beta_bvec_kernel(
    const unsigned short* __restrict__ ctxp, const float* __restrict__ q2c,
    const float* __restrict__ cmask, float* __restrict__ bvec) {
  __shared__ float sh[C_];
  __shared__ float red[256];
  const int tid = threadIdx.x;
  const int b = blockIdx.x / 12;
  const int p0 = (blockIdx.x % 12) * 64;
  float v[4];
  float lm = -1e30f;
#pragma unroll
  for (int i = 0; i < 4; ++i) {
    v[i] = q2c[b * C_ + i * 256 + tid];
    lm = fmaxf(lm, v[i]);
  }
  red[tid] = lm;
  __syncthreads();
  for (int off = 128; off > 0; off >>= 1) {
    if (tid < off) red[tid] = fmaxf(red[tid], red[tid + off]);
    __syncthreads();
  }
  const float m = red[0];
  __syncthreads();
  float ls = 0.f;
#pragma unroll
  for (int i = 0; i < 4; ++i) {
    float e = __expf(v[i] - m);
    sh[i * 256 + tid] = e * cmask[b * C_ + i * 256 + tid];
    ls += e;
  }
  red[tid] = ls;
  __syncthreads();
  for (int off = 128; off > 0; off >>= 1) {
    if (tid < off) red[tid] += red[tid + off];
    __syncthreads();
  }
  const float denom = red[0];
  const int pp = tid & 63;
  const int cg = tid >> 6;
  const unsigned short* base = ctxp + ((size_t)(b * C_ + cg)) * H_ + p0 + pp;
  float acc = 0.f;
#pragma unroll 4
  for (int c = cg; c < C_; c += 4) {
    acc += sh[c] * bf2f(*base);
    base += (size_t)4 * H_;
  }
  __syncthreads();
  red[tid] = acc;
  __syncthreads();
  if (tid < 64)
    bvec[b * H_ + p0 + tid] =
        (red[tid] + red[tid + 64] + red[tid + 128] + red[tid + 192]) / denom;
}

extern "C" void kernel_launch(void* const* d_in, const int* in_sizes, int n_in,
                              void* d_out, int out_size, void* d_ws, size_t ws_size,
                              hipStream_t stream) {
  const float* context = (const float*)d_in[0];
  const float* cmask   = (const float*)d_in[1];
  const float* query   = (const float*)d_in[2];
  const float* qmask   = (const float*)d_in[3];
  const float* Wc      = (const float*)d_in[4];
  const float* bc      = (const float*)d_in[5];
  const float* Wq      = (const float*)d_in[6];
  const float* bq      = (const float*)d_in[7];
  const float* w_att   = (const float*)d_in[8];
  float* out = (float*)d_out;

  unsigned short* ws_ctxb = (unsigned short*)d_ws;
  unsigned short* ws_qinb = ws_ctxb + (size_t)B_ * C_ * H_;
  unsigned short* ws_Wcb  = ws_qinb + (size_t)B_ * Q_ * H_;
  unsigned short* ws_Wqb  = ws_Wcb + (size_t)H_ * H_;
  unsigned short* ws_qryW = ws_Wqb + (size_t)H_ * H_;
  unsigned short* ws_qryT = ws_qryW + (size_t)B_ * Q_ * H_;
  unsigned short* ws_ctxp = ws_qryT + (size_t)B_ * H_ * Q_;
  float* ws_q2c  = (float*)(ws_ctxp + (size_t)B_ * C_ * H_);
  float* ws_bvec = ws_q2c + (size_t)B_ * C_;
  unsigned short* ws_alpha = ws_qinb;  // overlays dead qinb+Wcb

  {
    const int n0 = B_ * C_ * H_ / 8;
    const int n1 = B_ * Q_ * H_ / 8;
    const int n2 = H_ * H_ / 8;
    const int n3 = n2;
    const int tot = n0 + n1 + n2 + n3;
    f2bf4_kernel<<<(tot + 255) / 256, 256, 0, stream>>>(
        context, ws_ctxb, n0, query, ws_qinb, n1, Wc, ws_Wcb, n2, Wq, ws_Wqb, n3);
  }
  // qry projection: qryW (w_att folded) + qryT. 96 blocks, qchunk=12.
  gemm_uni<1><<<96, 256, 0, stream>>>(
      ws_qinb, ws_Wqb, bq, nullptr, ws_qryW, ws_qryT, w_att,
      nullptr, nullptr, nullptr, nullptr, H_, 12);
  // ctx projection: fp32 out (stride 4H) + bf16 ctxp. 768 blocks, qchunk=96.
  gemm_uni<0><<<768, 256, 0, stream>>>(
      ws_ctxb, ws_Wcb, bc, out, ws_ctxp, nullptr, nullptr,
      nullptr, nullptr, nullptr, nullptr, H_, 96);
  // sim GEMM + fused softmax: alpha (bf16) + q2c. 128 blocks, qchunk=16.
  gemm_uni<2><<<128, 256, 0, stream>>>(
      ws_ctxp, ws_qryW, nullptr, nullptr, ws_alpha, nullptr, nullptr,
      cmask, qmask, ws_q2c, nullptr, H_, 16);
  // beta softmax + bvec (reads bf16 ctxp). 192 blocks.
  beta_bvec_kernel<<<B_ * 12, 256, 0, stream>>>(ws_ctxp, ws_q2c, cmask, ws_bvec);
  // PV GEMM: writes a, c=ctx*a, d=ctx*bvec. 768 blocks, K=128, qchunk=96.
  gemm_uni<3><<<768, 256, 0, stream>>>(
      ws_alpha, ws_qryT, nullptr, out, ws_ctxp, nullptr, nullptr,
      nullptr, nullptr, nullptr, ws_bvec, Q_, 96);
}

// Round 11
// 161.363 us; speedup vs baseline: 1.7879x; 1.1087x over previous
//
#include <hip/hip_runtime.h>
#include <cstdint>

#define B_ 16
#define C_ 1024
#define Q_ 128
#define H_ 768
#define OSTR (4 * H_)  // 3072

typedef __attribute__((ext_vector_type(8))) short bf16x8;
typedef __attribute__((ext_vector_type(4))) float f32x4;
typedef __attribute__((ext_vector_type(4))) int int4v;

__device__ __forceinline__ unsigned short f2bf(float x) {
  union { float f; unsigned u; } v; v.f = x;
  unsigned r = v.u + 0x7FFFu + ((v.u >> 16) & 1u);
  return (unsigned short)(r >> 16);
}
__device__ __forceinline__ unsigned pk2(float a, float b) {
  return (unsigned)f2bf(a) | ((unsigned)f2bf(b) << 16);
}
__device__ __forceinline__ float bf2f(unsigned short u) {
  union { unsigned u; float f; } t; t.u = ((unsigned)u) << 16; return t.f;
}

// four-segment fp32 -> bf16 (context, query, Wc, Wq) in one launch
__global__ __launch_bounds__(256) void f2bf4_kernel(
    const float* __restrict__ s0, unsigned short* __restrict__ d0, int n0,
    const float* __restrict__ s1, unsigned short* __restrict__ d1, int n1,
    const float* __restrict__ s2, unsigned short* __restrict__ d2, int n2,
    const float* __restrict__ s3, unsigned short* __restrict__ d3, int n3) {
  int i = blockIdx.x * 256 + threadIdx.x;
  const float* s;
  unsigned short* d;
  if (i < n0) { s = s0; d = d0; }
  else if ((i -= n0) < n1) { s = s1; d = d1; }
  else if ((i -= n1) < n2) { s = s2; d = d2; }
  else if ((i -= n2) < n3) { s = s3; d = d3; }
  else return;
  float4 a = ((const float4*)s)[2 * i];
  float4 b = ((const float4*)s)[2 * i + 1];
  int4v o;
  o[0] = (int)pk2(a.x, a.y); o[1] = (int)pk2(a.z, a.w);
  o[2] = (int)pk2(b.x, b.y); o[3] = (int)pk2(b.z, b.w);
  ((int4v*)d)[i] = o;
}

// Unified NT GEMM, global_load_lds staging, bijective XCD-chunked swizzle.
// MODE 0: ctx proj (128x128) -> bf16 ctxp ONLY (LDS bf16-transpose, int4v stores)
// MODE 1: qry proj (128x128) -> bf16 qryW=v*watt (ob1) + bf16 qryT (ob2)
// MODE 2: sim (64x128, full q) -> fused row-softmax -> bf16 alpha (ob1) + q2c
// MODE 3: PV (64x128, K=128) -> writes ALL 4 out sections: ctx, a, c, d
//         (ctxp tile prefetched before K-loop; fp32 LDS transpose; float4 stores)
template <int MODE>
__global__ __launch_bounds__(256) void gemm_uni(
    const unsigned short* __restrict__ A, const unsigned short* __restrict__ Bm,
    const float* __restrict__ bias, float* __restrict__ out32,
    unsigned short* __restrict__ ob1, unsigned short* __restrict__ ob2,
    const float* __restrict__ watt, const float* __restrict__ cmask,
    const float* __restrict__ qmask, float* __restrict__ q2c,
    const float* __restrict__ bvec, int K, int qchunk) {
  __shared__ __align__(16) unsigned char smem[(MODE == 0 || MODE == 3) ? 33792 : 16384];
  __shared__ float pmS[2][64];
  __shared__ float psS[2][64];
  constexpr int AROWS = (MODE < 2) ? 128 : 64;  // A-tile rows
  constexpr int MI = (MODE < 2) ? 4 : 2;        // row frags per wave
  unsigned short* As = (unsigned short*)smem;
  unsigned short* Ws = (unsigned short*)(smem + ((MODE < 2) ? 8192 : 4096));
  const int tid = threadIdx.x;
  const int lane = tid & 63;
  const int w = tid >> 6;
  const int orig = ((int)blockIdx.x & 7) * qchunk + ((int)blockIdx.x >> 3);
  const int wrA = (w >> 1) * (AROWS / 2);
  const int wcB = (w & 1) * 64;
  const int fr = lane & 15;
  const int fq = lane >> 4;

  int gm, gn, bb;
  const unsigned short *Ap, *Bp;
  if constexpr (MODE == 0 || MODE == 1) {
    gm = (orig / 6) * 128; gn = (orig % 6) * 128; bb = 0;
    Ap = A + (size_t)gm * K; Bp = Bm + (size_t)gn * K;
  } else if constexpr (MODE == 2) {
    bb = orig >> 4; gm = bb * C_ + (orig & 15) * 64; gn = 0;
    Ap = A + (size_t)gm * K; Bp = Bm + (size_t)bb * Q_ * K;
  } else {
    bb = orig / 96; const int rem = orig % 96;
    gm = bb * C_ + (rem / 6) * 64; gn = (rem % 6) * 128;
    Ap = A + (size_t)gm * K; Bp = Bm + ((size_t)bb * H_ + gn) * K;
  }

  auto stage128 = [&](const unsigned short* __restrict__ G, unsigned short* S, int k0) {
#pragma unroll
    for (int r = 0; r < 2; ++r) {
      const int c = r * 256 + tid;
      const int row = c >> 2, sub = c & 3;
      const unsigned short* g = G + (size_t)row * K + k0 + sub * 8;
      unsigned short* l = S + (size_t)(r * 256 + w * 64) * 8;  // wave-uniform base
      __builtin_amdgcn_global_load_lds(
          (const __attribute__((address_space(1))) void*)g,
          (__attribute__((address_space(3))) void*)l, 16, 0, 0);
    }
  };
  auto stage64 = [&](const unsigned short* __restrict__ G, unsigned short* S, int k0) {
    const int c = tid;
    const int row = c >> 2, sub = c & 3;
    const unsigned short* g = G + (size_t)row * K + k0 + sub * 8;
    unsigned short* l = S + (size_t)(w * 64) * 8;  // wave-uniform base
    __builtin_amdgcn_global_load_lds(
        (const __attribute__((address_space(1))) void*)g,
        (__attribute__((address_space(3))) void*)l, 16, 0, 0);
  };

  // MODE 3: prefetch the ctxp tile in OUTPUT layout before the K-loop (T14).
  ushort4 cxr[8];
  if constexpr (MODE == 3) {
#pragma unroll
    for (int k = 0; k < 8; ++k) {
      const int f = k * 256 + tid;
      const int row = f >> 5, c4 = (f & 31) << 2;
      cxr[k] = *(const ushort4*)&ob1[(size_t)(gm + row) * H_ + gn + c4];
    }
  }

  f32x4 acc[MI][4];
#pragma unroll
  for (int i = 0; i < MI; ++i)
#pragma unroll
    for (int j = 0; j < 4; ++j)
#pragma unroll
      for (int e = 0; e < 4; ++e) acc[i][j][e] = 0.f;

  for (int k0 = 0; k0 < K; k0 += 32) {
    if constexpr (MODE < 2) stage128(Ap, As, k0); else stage64(Ap, As, k0);
    stage128(Bp, Ws, k0);
    __syncthreads();
    bf16x8 af[MI], wf[4];
#pragma unroll
    for (int i = 0; i < MI; ++i)
      af[i] = *(const bf16x8*)(As + (wrA + i * 16 + fr) * 32 + fq * 8);
#pragma unroll
    for (int j = 0; j < 4; ++j)
      wf[j] = *(const bf16x8*)(Ws + (wcB + j * 16 + fr) * 32 + fq * 8);
#pragma unroll
    for (int i = 0; i < MI; ++i)
#pragma unroll
      for (int j = 0; j < 4; ++j)
        acc[i][j] = __builtin_amdgcn_mfma_f32_16x16x32_bf16(af[i], wf[j], acc[i][j], 0, 0, 0);
    __syncthreads();
  }

  if constexpr (MODE == 0) {
    // bf16 transpose in LDS -> coalesced int4v stores of ctxp only
    unsigned short* tr16 = (unsigned short*)smem;
    float bj[4];
#pragma unroll
    for (int j = 0; j < 4; ++j) bj[j] = bias[gn + wcB + j * 16 + fr];
#pragma unroll
    for (int i = 0; i < 4; ++i)
#pragma unroll
      for (int j = 0; j < 4; ++j)
#pragma unroll
        for (int r = 0; r < 4; ++r)
          tr16[(wrA + i * 16 + fq * 4 + r) * 132 + wcB + j * 16 + fr] =
              f2bf(acc[i][j][r] + bj[j]);
    __syncthreads();
#pragma unroll
    for (int k = 0; k < 8; ++k) {
      const int f = k * 256 + tid;
      const int row = f >> 4, c8 = (f & 15) << 3;
      int4v v = *(const int4v*)&tr16[row * 132 + c8];
      *(int4v*)&ob1[(size_t)(gm + row) * H_ + gn + c8] = v;
    }
  } else if constexpr (MODE == 1) {
#pragma unroll
    for (int i = 0; i < 4; ++i) {
#pragma unroll
      for (int j = 0; j < 4; ++j) {
        const int n = gn + wcB + j * 16 + fr;
        const float bias_n = bias[n];
        const float wv = watt[n];
        ushort4 t4;
#pragma unroll
        for (int r = 0; r < 4; ++r) {
          const size_t m = (size_t)gm + wrA + i * 16 + fq * 4 + r;
          float v = acc[i][j][r] + bias_n;
          ob1[m * H_ + n] = f2bf(v * wv);
          (&t4.x)[r] = f2bf(v);
        }
        const int bidx = gm >> 7;
        const int q0 = wrA + i * 16 + fq * 4;
        *(ushort4*)(ob2 + ((size_t)bidx * H_ + n) * Q_ + q0) = t4;
      }
    }
  } else if constexpr (MODE == 2) {
    // fused row-softmax over the full 128-wide q dim (64 rows per block)
    float red[MI][4];
#pragma unroll
    for (int i = 0; i < MI; ++i)
#pragma unroll
      for (int r = 0; r < 4; ++r) {
        float mx = acc[i][0][r];
#pragma unroll
        for (int j = 1; j < 4; ++j) mx = fmaxf(mx, acc[i][j][r]);
        mx = fmaxf(mx, __shfl_xor(mx, 1));
        mx = fmaxf(mx, __shfl_xor(mx, 2));
        mx = fmaxf(mx, __shfl_xor(mx, 4));
        mx = fmaxf(mx, __shfl_xor(mx, 8));
        if (fr == 0) pmS[w & 1][wrA + i * 16 + fq * 4 + r] = mx;
      }
    __syncthreads();
    float qm[4];
#pragma unroll
    for (int j = 0; j < 4; ++j) qm[j] = qmask[bb * Q_ + wcB + j * 16 + fr];
#pragma unroll
    for (int i = 0; i < MI; ++i)
#pragma unroll
      for (int r = 0; r < 4; ++r) {
        const int lr = wrA + i * 16 + fq * 4 + r;
        const float M = fmaxf(pmS[0][lr], pmS[1][lr]);
        if ((w & 1) == 0 && fr == 0) q2c[gm + lr] = M;  // b_att cancels in both softmaxes
        float s = 0.f;
#pragma unroll
        for (int j = 0; j < 4; ++j) {
          acc[i][j][r] = __expf(acc[i][j][r] - M);
          s += acc[i][j][r];
        }
        s += __shfl_xor(s, 1); s += __shfl_xor(s, 2);
        s += __shfl_xor(s, 4); s += __shfl_xor(s, 8);
        if (fr == 0) psS[w & 1][lr] = s;
      }
    __syncthreads();
#pragma unroll
    for (int i = 0; i < MI; ++i)
#pragma unroll
      for (int r = 0; r < 4; ++r) {
        const int lr = wrA + i * 16 + fq * 4 + r;
        const float S = psS[0][lr] + psS[1][lr];
        const float inv = cmask[gm + lr] / S;
#pragma unroll
        for (int j = 0; j < 4; ++j) {
          const int lc = wcB + j * 16 + fr;
          ob1[(size_t)(gm + lr) * Q_ + lc] = f2bf(acc[i][j][r] * inv * qm[j]);
        }
      }
  } else {  // MODE 3: fp32 transpose -> write ctx, a, c, d (full output rows)
    float* tr = (float*)smem;
#pragma unroll
    for (int i = 0; i < MI; ++i)
#pragma unroll
      for (int j = 0; j < 4; ++j)
#pragma unroll
        for (int r = 0; r < 4; ++r)
          tr[(wrA + i * 16 + fq * 4 + r) * 132 + wcB + j * 16 + fr] = acc[i][j][r];
    __syncthreads();
#pragma unroll
    for (int k = 0; k < 8; ++k) {
      const int f = k * 256 + tid;
      const int row = f >> 5, c4 = (f & 31) << 2;
      float4 av = *(const float4*)&tr[row * 132 + c4];
      const ushort4 cu = cxr[k];
      float4 bv = *(const float4*)&bvec[bb * H_ + gn + c4];
      const float cx0 = bf2f(cu.x), cx1 = bf2f(cu.y), cx2 = bf2f(cu.z), cx3 = bf2f(cu.w);
      float* rowp = out32 + (size_t)(gm + row) * OSTR + gn;
      float4 cxv; cxv.x = cx0; cxv.y = cx1; cxv.z = cx2; cxv.w = cx3;
      *(float4*)&rowp[c4] = cxv;
      *(float4*)&rowp[H_ + c4] = av;
      float4 cc;
      cc.x = cx0 * av.x; cc.y = cx1 * av.y; cc.z = cx2 * av.z; cc.w = cx3 * av.w;
      *(float4*)&rowp[2 * H_ + c4] = cc;
      float4 dd;
      dd.x = cx0 * bv.x; dd.y = cx1 * bv.y; dd.z = cx2 * bv.z; dd.w = cx3 * bv.w;
      *(float4*)&rowp[3 * H_ + c4] = dd;
    }
  }
}

// beta softmax over c (per batch) + bvec[b,p] = sum_c beta[c]*ctx_bf16[b,c,p]
__global__ __launch_bounds__(256) void beta_bvec_kernel(
    const unsigned short* __restrict__ ctxp, const float* __restrict__ q2c,
    const float* __restrict__ cmask, float* __restrict__ bvec) {
  __shared__ float sh[C_];
  __shared__ float red[256];
  const int tid = threadIdx.x;
  const int b = blockIdx.x / 12;
  const int p0 = (blockIdx.x % 12) * 64;
  float v[4];
  float lm = -1e30f;
#pragma unroll
  for (int i = 0; i < 4; ++i) {
    v[i] = q2c[b * C_ + i * 256 + tid];
    lm = fmaxf(lm, v[i]);
  }
  red[tid] = lm;
  __syncthreads();
  for (int off = 128; off > 0; off >>= 1) {
    if (tid < off) red[tid] = fmaxf(red[tid], red[tid + off]);
    __syncthreads();
  }
  const float m = red[0];
  __syncthreads();
  float ls = 0.f;
#pragma unroll
  for (int i = 0; i < 4; ++i) {
    float e = __expf(v[i] - m);
    sh[i * 256 + tid] = e * cmask[b * C_ + i * 256 + tid];
    ls += e;
  }
  red[tid] = ls;
  __syncthreads();
  for (int off = 128; off > 0; off >>= 1) {
    if (tid < off) red[tid] += red[tid + off];
    __syncthreads();
  }
  const float denom = red[0];
  const int pp = tid & 63;
  const int cg = tid >> 6;
  const unsigned short* base = ctxp + ((size_t)(b * C_ + cg)) * H_ + p0 + pp;
  float acc = 0.f;
#pragma unroll 4
  for (int c = cg; c < C_; c += 4) {
    acc += sh[c] * bf2f(*base);
    base += (size_t)4 * H_;
  }
  __syncthreads();
  red[tid] = acc;
  __syncthreads();
  if (tid < 64)
    bvec[b * H_ + p0 + tid] =
        (red[tid] + red[tid + 64] + red[tid + 128] + red[tid + 192]) / denom;
}

extern "C" void kernel_launch(void* const* d_in, const int* in_sizes, int n_in,
                              void* d_out, int out_size, void* d_ws, size_t ws_size,
                              hipStream_t stream) {
  const float* context = (const float*)d_in[0];
  const float* cmask   = (const float*)d_in[1];
  const float* query   = (const float*)d_in[2];
  const float* qmask   = (const float*)d_in[3];
  const float* Wc      = (const float*)d_in[4];
  const float* bc      = (const float*)d_in[5];
  const float* Wq      = (const float*)d_in[6];
  const float* bq      = (const float*)d_in[7];
  const float* w_att   = (const float*)d_in[8];
  float* out = (float*)d_out;

  unsigned short* ws_ctxb = (unsigned short*)d_ws;
  unsigned short* ws_qinb = ws_ctxb + (size_t)B_ * C_ * H_;
  unsigned short* ws_Wcb  = ws_qinb + (size_t)B_ * Q_ * H_;
  unsigned short* ws_Wqb  = ws_Wcb + (size_t)H_ * H_;
  unsigned short* ws_qryW = ws_Wqb + (size_t)H_ * H_;
  unsigned short* ws_qryT = ws_qryW + (size_t)B_ * Q_ * H_;
  unsigned short* ws_ctxp = ws_qryT + (size_t)B_ * H_ * Q_;
  float* ws_q2c  = (float*)(ws_ctxp + (size_t)B_ * C_ * H_);
  float* ws_bvec = ws_q2c + (size_t)B_ * C_;
  unsigned short* ws_alpha = ws_qinb;  // overlays dead qinb+Wcb

  {
    const int n0 = B_ * C_ * H_ / 8;
    const int n1 = B_ * Q_ * H_ / 8;
    const int n2 = H_ * H_ / 8;
    const int n3 = n2;
    const int tot = n0 + n1 + n2 + n3;
    f2bf4_kernel<<<(tot + 255) / 256, 256, 0, stream>>>(
        context, ws_ctxb, n0, query, ws_qinb, n1, Wc, ws_Wcb, n2, Wq, ws_Wqb, n3);
  }
  // qry projection: qryW (w_att folded) + qryT. 96 blocks, qchunk=12.
  gemm_uni<1><<<96, 256, 0, stream>>>(
      ws_qinb, ws_Wqb, bq, nullptr, ws_qryW, ws_qryT, w_att,
      nullptr, nullptr, nullptr, nullptr, H_, 12);
  // ctx projection -> bf16 ctxp ONLY. 768 blocks, qchunk=96.
  gemm_uni<0><<<768, 256, 0, stream>>>(
      ws_ctxb, ws_Wcb, bc, nullptr, ws_ctxp, nullptr, nullptr,
      nullptr, nullptr, nullptr, nullptr, H_, 96);
  // sim GEMM + fused softmax: alpha bf16 + q2c. 256 blocks (64-row), qchunk=32.
  gemm_uni<2><<<256, 256, 0, stream>>>(
      ws_ctxp, ws_qryW, nullptr, nullptr, ws_alpha, nullptr, nullptr,
      cmask, qmask, ws_q2c, nullptr, H_, 32);
  // beta softmax + bvec (reads bf16 ctxp). 192 blocks.
  beta_bvec_kernel<<<B_ * 12, 256, 0, stream>>>(ws_ctxp, ws_q2c, cmask, ws_bvec);
  // PV GEMM: writes ALL of out (ctx, a, c, d). 1536 blocks (64-row), qchunk=192.
  gemm_uni<3><<<1536, 256, 0, stream>>>(
      ws_alpha, ws_qryT, nullptr, out, ws_ctxp, nullptr, nullptr,
      nullptr, nullptr, nullptr, ws_bvec, Q_, 192);
}

// Round 12
// 161.183 us; speedup vs baseline: 1.7899x; 1.0011x over previous
//
#include <hip/hip_runtime.h>
#include <cstdint>

#define B_ 16
#define C_ 1024
#define Q_ 128
#define H_ 768
#define OSTR (4 * H_)  // 3072

typedef __attribute__((ext_vector_type(8))) short bf16x8;
typedef __attribute__((ext_vector_type(4))) float f32x4;
typedef __attribute__((ext_vector_type(4))) int int4v;

__device__ __forceinline__ unsigned short f2bf(float x) {
  union { float f; unsigned u; } v; v.f = x;
  unsigned r = v.u + 0x7FFFu + ((v.u >> 16) & 1u);
  return (unsigned short)(r >> 16);
}
__device__ __forceinline__ unsigned pk2(float a, float b) {
  return (unsigned)f2bf(a) | ((unsigned)f2bf(b) << 16);
}
__device__ __forceinline__ float bf2f(unsigned short u) {
  union { unsigned u; float f; } t; t.u = ((unsigned)u) << 16; return t.f;
}

// four-segment fp32 -> bf16 (context, query, Wc, Wq) in one launch
__global__ __launch_bounds__(256) void f2bf4_kernel(
    const float* __restrict__ s0, unsigned short* __restrict__ d0, int n0,
    const float* __restrict__ s1, unsigned short* __restrict__ d1, int n1,
    const float* __restrict__ s2, unsigned short* __restrict__ d2, int n2,
    const float* __restrict__ s3, unsigned short* __restrict__ d3, int n3) {
  int i = blockIdx.x * 256 + threadIdx.x;
  const float* s;
  unsigned short* d;
  if (i < n0) { s = s0; d = d0; }
  else if ((i -= n0) < n1) { s = s1; d = d1; }
  else if ((i -= n1) < n2) { s = s2; d = d2; }
  else if ((i -= n2) < n3) { s = s3; d = d3; }
  else return;
  float4 a = ((const float4*)s)[2 * i];
  float4 b = ((const float4*)s)[2 * i + 1];
  int4v o;
  o[0] = (int)pk2(a.x, a.y); o[1] = (int)pk2(a.z, a.w);
  o[2] = (int)pk2(b.x, b.y); o[3] = (int)pk2(b.z, b.w);
  ((int4v*)d)[i] = o;
}

// Unified NT GEMM, global_load_lds staging, bijective XCD-chunked swizzle.
// MODE 0: ctx proj (128x128) -> bf16 ctxp ONLY (LDS bf16-transpose, int4v stores)
// MODE 1: qry proj (128x128) -> bf16 qryW=v*watt (ob1) + bf16 qryT (ob2)
// MODE 2: sim (64x128, full q) -> fused row-softmax -> bf16 alpha (ob1) + q2c
template <int MODE>
__global__ __launch_bounds__(256) void gemm_uni(
    const unsigned short* __restrict__ A, const unsigned short* __restrict__ Bm,
    const float* __restrict__ bias, unsigned short* __restrict__ ob1,
    unsigned short* __restrict__ ob2, const float* __restrict__ watt,
    const float* __restrict__ cmask, const float* __restrict__ qmask,
    float* __restrict__ q2c, int K, int qchunk) {
  __shared__ __align__(16) unsigned char smem[(MODE == 0) ? 33792 : 16384];
  __shared__ float pmS[2][64];
  __shared__ float psS[2][64];
  constexpr int AROWS = (MODE < 2) ? 128 : 64;  // A-tile rows
  constexpr int MI = (MODE < 2) ? 4 : 2;        // row frags per wave
  unsigned short* As = (unsigned short*)smem;
  unsigned short* Ws = (unsigned short*)(smem + ((MODE < 2) ? 8192 : 4096));
  const int tid = threadIdx.x;
  const int lane = tid & 63;
  const int w = tid >> 6;
  const int orig = ((int)blockIdx.x & 7) * qchunk + ((int)blockIdx.x >> 3);
  const int wrA = (w >> 1) * (AROWS / 2);
  const int wcB = (w & 1) * 64;
  const int fr = lane & 15;
  const int fq = lane >> 4;

  int gm, gn, bb;
  const unsigned short *Ap, *Bp;
  if constexpr (MODE == 0 || MODE == 1) {
    gm = (orig / 6) * 128; gn = (orig % 6) * 128; bb = 0;
    Ap = A + (size_t)gm * K; Bp = Bm + (size_t)gn * K;
  } else {
    bb = orig >> 4; gm = bb * C_ + (orig & 15) * 64; gn = 0;
    Ap = A + (size_t)gm * K; Bp = Bm + (size_t)bb * Q_ * K;
  }

  auto stage128 = [&](const unsigned short* __restrict__ G, unsigned short* S, int k0) {
#pragma unroll
    for (int r = 0; r < 2; ++r) {
      const int c = r * 256 + tid;
      const int row = c >> 2, sub = c & 3;
      const unsigned short* g = G + (size_t)row * K + k0 + sub * 8;
      unsigned short* l = S + (size_t)(r * 256 + w * 64) * 8;  // wave-uniform base
      __builtin_amdgcn_global_load_lds(
          (const __attribute__((address_space(1))) void*)g,
          (__attribute__((address_space(3))) void*)l, 16, 0, 0);
    }
  };
  auto stage64 = [&](const unsigned short* __restrict__ G, unsigned short* S, int k0) {
    const int c = tid;
    const int row = c >> 2, sub = c & 3;
    const unsigned short* g = G + (size_t)row * K + k0 + sub * 8;
    unsigned short* l = S + (size_t)(w * 64) * 8;  // wave-uniform base
    __builtin_amdgcn_global_load_lds(
        (const __attribute__((address_space(1))) void*)g,
        (__attribute__((address_space(3))) void*)l, 16, 0, 0);
  };

  f32x4 acc[MI][4];
#pragma unroll
  for (int i = 0; i < MI; ++i)
#pragma unroll
    for (int j = 0; j < 4; ++j)
#pragma unroll
      for (int e = 0; e < 4; ++e) acc[i][j][e] = 0.f;

  for (int k0 = 0; k0 < K; k0 += 32) {
    if constexpr (MODE < 2) stage128(Ap, As, k0); else stage64(Ap, As, k0);
    stage128(Bp, Ws, k0);
    __syncthreads();
    bf16x8 af[MI], wf[4];
#pragma unroll
    for (int i = 0; i < MI; ++i)
      af[i] = *(const bf16x8*)(As + (wrA + i * 16 + fr) * 32 + fq * 8);
#pragma unroll
    for (int j = 0; j < 4; ++j)
      wf[j] = *(const bf16x8*)(Ws + (wcB + j * 16 + fr) * 32 + fq * 8);
#pragma unroll
    for (int i = 0; i < MI; ++i)
#pragma unroll
      for (int j = 0; j < 4; ++j)
        acc[i][j] = __builtin_amdgcn_mfma_f32_16x16x32_bf16(af[i], wf[j], acc[i][j], 0, 0, 0);
    __syncthreads();
  }

  if constexpr (MODE == 0) {
    // bf16 transpose in LDS -> coalesced int4v stores of ctxp only
    unsigned short* tr16 = (unsigned short*)smem;
    float bj[4];
#pragma unroll
    for (int j = 0; j < 4; ++j) bj[j] = bias[gn + wcB + j * 16 + fr];
#pragma unroll
    for (int i = 0; i < 4; ++i)
#pragma unroll
      for (int j = 0; j < 4; ++j)
#pragma unroll
        for (int r = 0; r < 4; ++r)
          tr16[(wrA + i * 16 + fq * 4 + r) * 132 + wcB + j * 16 + fr] =
              f2bf(acc[i][j][r] + bj[j]);
    __syncthreads();
#pragma unroll
    for (int k = 0; k < 8; ++k) {
      const int f = k * 256 + tid;
      const int row = f >> 4, c8 = (f & 15) << 3;
      int4v v = *(const int4v*)&tr16[row * 132 + c8];
      *(int4v*)&ob1[(size_t)(gm + row) * H_ + gn + c8] = v;
    }
  } else if constexpr (MODE == 1) {
#pragma unroll
    for (int i = 0; i < 4; ++i) {
#pragma unroll
      for (int j = 0; j < 4; ++j) {
        const int n = gn + wcB + j * 16 + fr;
        const float bias_n = bias[n];
        const float wv = watt[n];
        ushort4 t4;
#pragma unroll
        for (int r = 0; r < 4; ++r) {
          const size_t m = (size_t)gm + wrA + i * 16 + fq * 4 + r;
          float v = acc[i][j][r] + bias_n;
          ob1[m * H_ + n] = f2bf(v * wv);
          (&t4.x)[r] = f2bf(v);
        }
        const int bidx = gm >> 7;
        const int q0 = wrA + i * 16 + fq * 4;
        *(ushort4*)(ob2 + ((size_t)bidx * H_ + n) * Q_ + q0) = t4;
      }
    }
  } else {  // MODE 2: fused row-softmax over the full 128-wide q dim
    float red[MI][4];
#pragma unroll
    for (int i = 0; i < MI; ++i)
#pragma unroll
      for (int r = 0; r < 4; ++r) {
        float mx = acc[i][0][r];
#pragma unroll
        for (int j = 1; j < 4; ++j) mx = fmaxf(mx, acc[i][j][r]);
        mx = fmaxf(mx, __shfl_xor(mx, 1));
        mx = fmaxf(mx, __shfl_xor(mx, 2));
        mx = fmaxf(mx, __shfl_xor(mx, 4));
        mx = fmaxf(mx, __shfl_xor(mx, 8));
        if (fr == 0) pmS[w & 1][wrA + i * 16 + fq * 4 + r] = mx;
      }
    __syncthreads();
    float qm[4];
#pragma unroll
    for (int j = 0; j < 4; ++j) qm[j] = qmask[bb * Q_ + wcB + j * 16 + fr];
#pragma unroll
    for (int i = 0; i < MI; ++i)
#pragma unroll
      for (int r = 0; r < 4; ++r) {
        const int lr = wrA + i * 16 + fq * 4 + r;
        const float M = fmaxf(pmS[0][lr], pmS[1][lr]);
        if ((w & 1) == 0 && fr == 0) q2c[gm + lr] = M;  // b_att cancels in both softmaxes
        float s = 0.f;
#pragma unroll
        for (int j = 0; j < 4; ++j) {
          acc[i][j][r] = __expf(acc[i][j][r] - M);
          s += acc[i][j][r];
        }
        s += __shfl_xor(s, 1); s += __shfl_xor(s, 2);
        s += __shfl_xor(s, 4); s += __shfl_xor(s, 8);
        if (fr == 0) psS[w & 1][lr] = s;
      }
    __syncthreads();
#pragma unroll
    for (int i = 0; i < MI; ++i)
#pragma unroll
      for (int r = 0; r < 4; ++r) {
        const int lr = wrA + i * 16 + fq * 4 + r;
        const float S = psS[0][lr] + psS[1][lr];
        const float inv = cmask[gm + lr] / S;
#pragma unroll
        for (int j = 0; j < 4; ++j) {
          const int lc = wcB + j * 16 + fr;
          ob1[(size_t)(gm + lr) * Q_ + lc] = f2bf(acc[i][j][r] * inv * qm[j]);
        }
      }
  }
}

// PV: a = alpha @ qryT^T (64x128 tile, K=128, no staged K-loop).
// B panel (32KB) staged to LDS once; A (alpha) fragments direct from global;
// epilogue writes all 4 output sections (ctx, a, c=ctx*a, d=ctx*bvec) coalesced.
__global__ __launch_bounds__(256) void pv_kernel(
    const unsigned short* __restrict__ alpha, const unsigned short* __restrict__ qryT,
    const unsigned short* __restrict__ ctxp, const float* __restrict__ bvec,
    float* __restrict__ out32) {
  __shared__ __align__(16) unsigned char smem[33792];
  const int tid = threadIdx.x;
  const int lane = tid & 63;
  const int w = tid >> 6;
  const int fr = lane & 15;
  const int fq = lane >> 4;
  const int orig = ((int)blockIdx.x & 7) * 192 + ((int)blockIdx.x >> 3);
  const int bb = orig / 96;
  const int rem = orig % 96;
  const int gm = bb * C_ + (rem / 6) * 64;
  const int gn = (rem % 6) * 128;
  const unsigned short* Ap = alpha + (size_t)gm * Q_;
  const unsigned short* Bp = qryT + ((size_t)bb * H_ + gn) * Q_;
  const int wrA = (w >> 1) * 32;
  const int wcB = (w & 1) * 64;
  unsigned short* Ws = (unsigned short*)smem;

  // stage full B panel (128 x 128 bf16 = 32 KB) via async gload_lds, one drain
#pragma unroll
  for (int kk = 0; kk < 4; ++kk) {
#pragma unroll
    for (int r = 0; r < 2; ++r) {
      const int c = r * 256 + tid;
      const int row = c >> 2, sub = c & 3;
      const unsigned short* g = Bp + (size_t)row * Q_ + kk * 32 + sub * 8;
      unsigned short* l = Ws + kk * 4096 + (size_t)(r * 256 + w * 64) * 8;
      __builtin_amdgcn_global_load_lds(
          (const __attribute__((address_space(1))) void*)g,
          (__attribute__((address_space(3))) void*)l, 16, 0, 0);
    }
  }
  // ctxp tile prefetch in output layout (T14: hides under MFMA phase)
  ushort4 cxr[8];
#pragma unroll
  for (int k = 0; k < 8; ++k) {
    const int f = k * 256 + tid;
    const int row = f >> 5, c4 = (f & 31) << 2;
    cxr[k] = *(const ushort4*)&ctxp[(size_t)(gm + row) * H_ + gn + c4];
  }
  // A (alpha) fragments direct from global — 4 MB buffer, L2-hot
  bf16x8 af[2][4];
#pragma unroll
  for (int i = 0; i < 2; ++i)
#pragma unroll
    for (int kk = 0; kk < 4; ++kk)
      af[i][kk] = *(const bf16x8*)(Ap + (size_t)(wrA + i * 16 + fr) * Q_ + kk * 32 + fq * 8);

  f32x4 acc[2][4];
#pragma unroll
  for (int i = 0; i < 2; ++i)
#pragma unroll
    for (int j = 0; j < 4; ++j)
#pragma unroll
      for (int e = 0; e < 4; ++e) acc[i][j][e] = 0.f;

  __syncthreads();  // B panel resident
#pragma unroll
  for (int kk = 0; kk < 4; ++kk) {
    bf16x8 wf[4];
#pragma unroll
    for (int j = 0; j < 4; ++j)
      wf[j] = *(const bf16x8*)(Ws + kk * 4096 + (wcB + j * 16 + fr) * 32 + fq * 8);
#pragma unroll
    for (int i = 0; i < 2; ++i)
#pragma unroll
      for (int j = 0; j < 4; ++j)
        acc[i][j] = __builtin_amdgcn_mfma_f32_16x16x32_bf16(af[i][kk], wf[j], acc[i][j], 0, 0, 0);
  }
  __syncthreads();  // done reading Ws; reuse as fp32 transpose buffer

  float* tr = (float*)smem;
#pragma unroll
  for (int i = 0; i < 2; ++i)
#pragma unroll
    for (int j = 0; j < 4; ++j)
#pragma unroll
      for (int r = 0; r < 4; ++r)
        tr[(wrA + i * 16 + fq * 4 + r) * 132 + wcB + j * 16 + fr] = acc[i][j][r];
  __syncthreads();
#pragma unroll
  for (int k = 0; k < 8; ++k) {
    const int f = k * 256 + tid;
    const int row = f >> 5, c4 = (f & 31) << 2;
    float4 av = *(const float4*)&tr[row * 132 + c4];
    const ushort4 cu = cxr[k];
    float4 bv = *(const float4*)&bvec[bb * H_ + gn + c4];
    const float cx0 = bf2f(cu.x), cx1 = bf2f(cu.y), cx2 = bf2f(cu.z), cx3 = bf2f(cu.w);
    float* rowp = out32 + (size_t)(gm + row) * OSTR + gn;
    float4 cxv; cxv.x = cx0; cxv.y = cx1; cxv.z = cx2; cxv.w = cx3;
    *(float4*)&rowp[c4] = cxv;
    *(float4*)&rowp[H_ + c4] = av;
    float4 cc;
    cc.x = cx0 * av.x; cc.y = cx1 * av.y; cc.z = cx2 * av.z; cc.w = cx3 * av.w;
    *(float4*)&rowp[2 * H_ + c4] = cc;
    float4 dd;
    dd.x = cx0 * bv.x; dd.y = cx1 * bv.y; dd.z = cx2 * bv.z; dd.w = cx3 * bv.w;
    *(float4*)&rowp[3 * H_ + c4] = dd;
  }
}

// beta softmax over c (per batch) + bvec[b,p] = sum_c beta[c]*ctx_bf16[b,c,p]
__global__ __launch_bounds__(256) void beta_bvec_kernel(
    const unsigned short* __restrict__ ctxp, const float* __restrict__ q2c,
    const float* __restrict__ cmask, float* __restrict__ bvec) {
  __shared__ float sh[C_];
  __shared__ float red[256];
  const int tid = threadIdx.x;
  const int b = blockIdx.x / 12;
  const int p0 = (blockIdx.x % 12) * 64;
  float v[4];
  float lm = -1e30f;
#pragma unroll
  for (int i = 0; i < 4; ++i) {
    v[i] = q2c[b * C_ + i * 256 + tid];
    lm = fmaxf(lm, v[i]);
  }
  red[tid] = lm;
  __syncthreads();
  for (int off = 128; off > 0; off >>= 1) {
    if (tid < off) red[tid] = fmaxf(red[tid], red[tid + off]);
    __syncthreads();
  }
  const float m = red[0];
  __syncthreads();
  float ls = 0.f;
#pragma unroll
  for (int i = 0; i < 4; ++i) {
    float e = __expf(v[i] - m);
    sh[i * 256 + tid] = e * cmask[b * C_ + i * 256 + tid];
    ls += e;
  }
  red[tid] = ls;
  __syncthreads();
  for (int off = 128; off > 0; off >>= 1) {
    if (tid < off) red[tid] += red[tid + off];
    __syncthreads();
  }
  const float denom = red[0];
  const int pp = tid & 63;
  const int cg = tid >> 6;
  const unsigned short* base = ctxp + ((size_t)(b * C_ + cg)) * H_ + p0 + pp;
  float acc = 0.f;
#pragma unroll 4
  for (int c = cg; c < C_; c += 4) {
    acc += sh[c] * bf2f(*base);
    base += (size_t)4 * H_;
  }
  __syncthreads();
  red[tid] = acc;
  __syncthreads();
  if (tid < 64)
    bvec[b * H_ + p0 + tid] =
        (red[tid] + red[tid + 64] + red[tid + 128] + red[tid + 192]) / denom;
}

extern "C" void kernel_launch(void* const* d_in, const int* in_sizes, int n_in,
                              void* d_out, int out_size, void* d_ws, size_t ws_size,
                              hipStream_t stream) {
  const float* context = (const float*)d_in[0];
  const float* cmask   = (const float*)d_in[1];
  const float* query   = (const float*)d_in[2];
  const float* qmask   = (const float*)d_in[3];
  const float* Wc      = (const float*)d_in[4];
  const float* bc      = (const float*)d_in[5];
  const float* Wq      = (const float*)d_in[6];
  const float* bq      = (const float*)d_in[7];
  const float* w_att   = (const float*)d_in[8];
  float* out = (float*)d_out;

  unsigned short* ws_ctxb = (unsigned short*)d_ws;
  unsigned short* ws_qinb = ws_ctxb + (size_t)B_ * C_ * H_;
  unsigned short* ws_Wcb  = ws_qinb + (size_t)B_ * Q_ * H_;
  unsigned short* ws_Wqb  = ws_Wcb + (size_t)H_ * H_;
  unsigned short* ws_qryW = ws_Wqb + (size_t)H_ * H_;
  unsigned short* ws_qryT = ws_qryW + (size_t)B_ * Q_ * H_;
  unsigned short* ws_ctxp = ws_qryT + (size_t)B_ * H_ * Q_;
  float* ws_q2c  = (float*)(ws_ctxp + (size_t)B_ * C_ * H_);
  float* ws_bvec = ws_q2c + (size_t)B_ * C_;
  unsigned short* ws_alpha = ws_qinb;  // overlays dead qinb+Wcb

  {
    const int n0 = B_ * C_ * H_ / 8;
    const int n1 = B_ * Q_ * H_ / 8;
    const int n2 = H_ * H_ / 8;
    const int n3 = n2;
    const int tot = n0 + n1 + n2 + n3;
    f2bf4_kernel<<<(tot + 255) / 256, 256, 0, stream>>>(
        context, ws_ctxb, n0, query, ws_qinb, n1, Wc, ws_Wcb, n2, Wq, ws_Wqb, n3);
  }
  // qry projection: qryW (w_att folded) + qryT. 96 blocks, qchunk=12.
  gemm_uni<1><<<96, 256, 0, stream>>>(
      ws_qinb, ws_Wqb, bq, ws_qryW, ws_qryT, w_att,
      nullptr, nullptr, nullptr, H_, 12);
  // ctx projection -> bf16 ctxp ONLY. 768 blocks, qchunk=96.
  gemm_uni<0><<<768, 256, 0, stream>>>(
      ws_ctxb, ws_Wcb, bc, ws_ctxp, nullptr, nullptr,
      nullptr, nullptr, nullptr, H_, 96);
  // sim GEMM + fused softmax: alpha bf16 + q2c. 256 blocks (64-row), qchunk=32.
  gemm_uni<2><<<256, 256, 0, stream>>>(
      ws_ctxp, ws_qryW, nullptr, ws_alpha, nullptr, nullptr,
      cmask, qmask, ws_q2c, H_, 32);
  // beta softmax + bvec (reads bf16 ctxp). 192 blocks.
  beta_bvec_kernel<<<B_ * 12, 256, 0, stream>>>(ws_ctxp, ws_q2c, cmask, ws_bvec);
  // PV: writes ALL of out (ctx, a, c, d). 1536 blocks (64-row), qchunk=192.
  pv_kernel<<<1536, 256, 0, stream>>>(ws_alpha, ws_qryT, ws_ctxp, ws_bvec, out);
}